// Round 2
// baseline (314.306 us; speedup 1.0000x reference)
//
#include <hip/hip_runtime.h>

#define NB 32
#define ND 64
#define NT 4096
#define NK 512
#define NGRID 1024

typedef __attribute__((ext_vector_type(8))) short short8;
typedef __attribute__((ext_vector_type(16))) float f32x16;
typedef unsigned int uint32;
typedef unsigned short ushort16_t;

#define PERM(r) ((((r) & 7) * 16) + ((r) >> 3))
#define STR 68
#define ESTR 66
// acc-domain margin: safe if > 2*eps_dot + emax/2 = ~1.8e-4 (emax = 64/512^2)
#define M2 4e-4f

__device__ __forceinline__ ushort16_t bf16rne(float f) {
    uint32 u = __float_as_uint(f);
    return (ushort16_t)((u + 0x7FFFu + ((u >> 16) & 1u)) >> 16);
}
__device__ __forceinline__ float bf16tof(ushort16_t h) {
    return __uint_as_float(((uint32)h) << 16);
}

// ---------------------------------------------------------------------------
// prep (verified R6-R8): blocks 0..15 pack cb into MFMA A-frags (bf16 hi/lo);
// block 16: exact numpy-pairwise enorm + zero loss accumulator/counter.
// ---------------------------------------------------------------------------
__global__ void prep_kernel(const float* __restrict__ cb,
                            uint4* __restrict__ cbfrag,
                            float* __restrict__ enorm,
                            double* __restrict__ loss_acc,
                            uint32* __restrict__ counter) {
    const int bi = blockIdx.x, tid = threadIdx.x;
    if (bi < 16) {
        const int t = bi * 256 + tid;
        const int c = t >> 8, rem = t & 255, s = rem >> 6, L = rem & 63;
        const int kcode = c * 32 + (L & 31);
        const int dbase = s * 16 + ((L >> 5) << 3);
        const float* src = cb + (size_t)kcode * 64 + dbase;
        const float4 pa = *(const float4*)src;
        const float4 pb = *(const float4*)(src + 4);
        const float f[8] = {pa.x, pa.y, pa.z, pa.w, pb.x, pb.y, pb.z, pb.w};
        uint32 hw[4], lw[4];
#pragma unroll
        for (int i = 0; i < 4; ++i) {
            const ushort16_t h0 = bf16rne(f[2*i]);
            const ushort16_t h1 = bf16rne(f[2*i+1]);
            const ushort16_t l0 = bf16rne(f[2*i]   - bf16tof(h0));
            const ushort16_t l1 = bf16rne(f[2*i+1] - bf16tof(h1));
            hw[i] = (uint32)h0 | ((uint32)h1 << 16);
            lw[i] = (uint32)l0 | ((uint32)l1 << 16);
        }
        cbfrag[(size_t)((c*4+s)*2 + 0)*64 + L] = make_uint4(hw[0],hw[1],hw[2],hw[3]);
        cbfrag[(size_t)((c*4+s)*2 + 1)*64 + L] = make_uint4(lw[0],lw[1],lw[2],lw[3]);
    } else {
        if (tid == 0) { *loss_acc = 0.0; *counter = 0u; }
        for (int k = tid; k < NK; k += 256) {
            const float* e = cb + (size_t)k * ND;
            float r[8];
#pragma unroll
            for (int j = 0; j < 8; ++j) {
                float s = __fmul_rn(e[j], e[j]);
#pragma unroll
                for (int i = 1; i < 8; ++i)
                    s = __fadd_rn(s, __fmul_rn(e[8*i+j], e[8*i+j]));
                r[j] = s;
            }
            enorm[k] = __fadd_rn(__fadd_rn(__fadd_rn(r[0],r[1]), __fadd_rn(r[2],r[3])),
                                 __fadd_rn(__fadd_rn(r[4],r[5]), __fadd_rn(r[6],r[7])));
        }
    }
}

// exact dist — the R1-R8 verified bit-exact chain
__device__ __forceinline__ float exact_dist(const float* __restrict__ zrow,
                                            const float* __restrict__ cb,
                                            const float* __restrict__ enl,
                                            float zn, int k2) {
    const float4* e4 = (const float4*)(cb + (size_t)k2 * ND);
    float a = 0.0f;
#pragma unroll
    for (int w = 0; w < 16; ++w) {
        const float4 ev = e4[w];
        const float4 zv = *(const float4*)(zrow + 4 * w);
        a = __builtin_fmaf(zv.x, ev.x, a);
        a = __builtin_fmaf(zv.y, ev.y, a);
        a = __builtin_fmaf(zv.z, ev.z, a);
        a = __builtin_fmaf(zv.w, ev.w, a);
    }
    return __fsub_rn(__fadd_rn(zn, enl[k2]), __fmul_rn(2.0f, a));
}

// ---------------------------------------------------------------------------
// R11 main: SINGLE-pass MFMA screen in acc domain (enorm folded into margin).
// Per-lane 4-deep register shift-list of packed (quantized-acc | k) rivals;
// threshold only rises, so screen-excluded k are below the final threshold.
// R11 fix vs R10: the LOSING half's local best is re-added as a rival after
// the cross-half combine (it is in neither list; the old two-pass kernel
// recollected it in pass B — single-pass must do it explicitly).
// Shift-out of a still-live candidate sets ovf -> exact full-scan fallback.
// ---------------------------------------------------------------------------
__global__ __launch_bounds__(256, 4) void vq_main(const float* __restrict__ z,
                                                  const float* __restrict__ cb,
                                                  const uint4* __restrict__ cbfrag,
                                                  const float* __restrict__ enorm,
                                                  float* __restrict__ qout,
                                                  float* __restrict__ idxout,
                                                  double* __restrict__ loss_acc,
                                                  uint32* __restrict__ counter,
                                                  float* __restrict__ out0) {
    __shared__ __align__(16) char smem[37920];
    float*       zl   = (float*)smem;              // 128 x STR (34816 B); later ech
    float*       enl  = (float*)(smem + 34816);    // 512 f32
    float*       znl  = (float*)(smem + 36864);    // 128 f32
    int*         sfin = (int*)(smem + 37376);      // 128
    double*      sred = (double*)(smem + 37888);   // 4

    const int bi    = blockIdx.x;                  // 1024
    const int b     = bi >> 5;
    const int tbase = (bi & 31) * 128;
    const int tid   = threadIdx.x;
    const size_t zoff = (size_t)b * (ND * NT) + tbase;

    // ---- stage z (verified transpose) ----
#pragma unroll
    for (int j = 0; j < 8; ++j) {
        const int qq = j * 256 + tid;
        const int i4 = qq & 31, d = qq >> 5;
        const float4 v = *(const float4*)(z + zoff + (size_t)d * NT + i4 * 4);
        const float vv[4] = {v.x, v.y, v.z, v.w};
#pragma unroll
        for (int c = 0; c < 4; ++c) {
            const int r = i4 * 4 + c;
            zl[PERM(r) * STR + d] = vv[c];
        }
    }
    for (int k = tid; k < NK; k += 256) enl[k] = enorm[k];
    __syncthreads();

    // ---- znorm (verified numpy pairwise, tid<128) ----
    if (tid < 128) {
        const int r = tid;
        const float4* zr4 = (const float4*)&zl[PERM(r) * STR];
        float x[64];
#pragma unroll
        for (int wq = 0; wq < 16; ++wq) {
            const float4 t4 = zr4[wq];
            x[4*wq] = t4.x; x[4*wq+1] = t4.y; x[4*wq+2] = t4.z; x[4*wq+3] = t4.w;
        }
        float r8[8];
#pragma unroll
        for (int jj = 0; jj < 8; ++jj) {
            float s = __fmul_rn(x[jj], x[jj]);
#pragma unroll
            for (int ii = 1; ii < 8; ++ii)
                s = __fadd_rn(s, __fmul_rn(x[8*ii+jj], x[8*ii+jj]));
            r8[jj] = s;
        }
        znl[r] = __fadd_rn(__fadd_rn(__fadd_rn(r8[0],r8[1]), __fadd_rn(r8[2],r8[3])),
                           __fadd_rn(__fadd_rn(r8[4],r8[5]), __fadd_rn(r8[6],r8[7])));
    }

    // ---- B-frags (verified: z rows bf16 hi/lo, same slot->d rule as prep) ----
    const int L    = tid & 63;
    const int w    = tid >> 6;
    const int h    = L >> 5;
    const int rowl = w * 32 + (L & 31);
    short8 bhf[4], blf[4];
    {
        const float* zrow = &zl[PERM(rowl) * STR];
#pragma unroll
        for (int s = 0; s < 4; ++s) {
            const int d0 = s * 16 + h * 8;
            const float4 pa = *(const float4*)(zrow + d0);
            const float4 pb = *(const float4*)(zrow + d0 + 4);
            const float f[8] = {pa.x, pa.y, pa.z, pa.w, pb.x, pb.y, pb.z, pb.w};
            uint32 hw[4], lw[4];
#pragma unroll
            for (int i = 0; i < 4; ++i) {
                const ushort16_t h0 = bf16rne(f[2*i]);
                const ushort16_t h1 = bf16rne(f[2*i+1]);
                const ushort16_t l0 = bf16rne(f[2*i]   - bf16tof(h0));
                const ushort16_t l1 = bf16rne(f[2*i+1] - bf16tof(h1));
                hw[i] = (uint32)h0 | ((uint32)h1 << 16);
                lw[i] = (uint32)l0 | ((uint32)l1 << 16);
            }
            union { uint4 u; short8 s8; } uh, ul;
            uh.u = make_uint4(hw[0],hw[1],hw[2],hw[3]);
            ul.u = make_uint4(lw[0],lw[1],lw[2],lw[3]);
            bhf[s] = uh.s8; blf[s] = ul.s8;
        }
    }
    __syncthreads();

    // ---- SINGLE-pass screen: acc-domain best + register rival shift-list ----
    // pack(v,k) = (bits(v + 0.5) & ~511) | k ; v in (-0.5,0.5) so v+0.5 > 0
    // => bit pattern is monotone in v; round-down => filter is superset-safe.
    float  bmax = -__builtin_inff();
    int    bk   = 0;
    float  thr  = -__builtin_inff();
    uint32 thrq = 0xFFFFFFFFu;       // q(thr); sentinel: never flags ovf early
    uint32 r0 = 0u, r1 = 0u, r2 = 0u, r3 = 0u;
    int    ovf  = 0;
    {
        uint4 buf0[8], buf1[8];
#pragma unroll
        for (int p = 0; p < 8; ++p) buf0[p] = cbfrag[(size_t)p * 64 + L];
#pragma unroll 2
        for (int c = 0; c < 16; ++c) {
            const uint4* cur = (c & 1) ? buf1 : buf0;
            uint4*       nxt = (c & 1) ? buf0 : buf1;
#pragma unroll
            for (int p = 0; p < 8; ++p)            // c=15 prefetch hits ws slack
                nxt[p] = cbfrag[(size_t)((c + 1) * 8 + p) * 64 + L];
            f32x16 acc;
#pragma unroll
            for (int r = 0; r < 16; ++r) acc[r] = 0.0f;
#pragma unroll
            for (int s = 0; s < 4; ++s) {
                union { uint4 u; short8 s8; } ah, al;
                ah.u = cur[s * 2 + 0];
                al.u = cur[s * 2 + 1];
                acc = __builtin_amdgcn_mfma_f32_32x32x16_bf16(ah.s8, bhf[s], acc, 0, 0, 0);
                acc = __builtin_amdgcn_mfma_f32_32x32x16_bf16(al.s8, bhf[s], acc, 0, 0, 0);
                acc = __builtin_amdgcn_mfma_f32_32x32x16_bf16(ah.s8, blf[s], acc, 0, 0, 0);
            }
#pragma unroll
            for (int r = 0; r < 16; ++r) {
                const float a = acc[r];
                if (a >= thr) {                    // rare after early iters
                    const int kc = c * 32 + ((r & 3) + 8 * (r >> 2) + 4 * h);
                    if (a > bmax) {
                        if (bmax >= a - M2) {      // dethroned best stays rival
                            const uint32 pv =
                                (__float_as_uint(bmax + 0.5f) & ~0x1FFu) | (uint32)bk;
                            ovf |= ((r3 & ~0x1FFu) >= thrq) ? 1 : 0;
                            r3 = r2; r2 = r1; r1 = r0; r0 = pv;
                        }
                        bmax = a; bk = kc;
                        thr  = a - M2;             // threshold only rises
                        thrq = __float_as_uint(thr + 0.5f) & ~0x1FFu;
                    } else {
                        const uint32 pv =
                            (__float_as_uint(a + 0.5f) & ~0x1FFu) | (uint32)kc;
                        ovf |= ((r3 & ~0x1FFu) >= thrq) ? 1 : 0;
                        r3 = r2; r2 = r1; r1 = r0; r0 = pv;
                    }
                }
            }
        }
    }

    // save the per-half local best BEFORE the combine (R11 fix)
    const float bmaxL = bmax;
    const int   bkL   = bk;

    // cross-half combine of screen best (lexicographic -> first occurrence)
    {
        const float ob  = __shfl_xor(bmax, 32);
        const int   obk = __shfl_xor(bk, 32);
        if (ob > bmax || (ob == bmax && obk < bk)) { bmax = ob; bk = obk; }
    }
    const float  thrf = bmax - M2;
    const uint32 thrF = __float_as_uint(thrf + 0.5f) & ~0x1FFu;
    // losing half's local best is in neither list: re-add it as a rival
    const int lbRival = (bkL != bk) && (bmaxL >= thrf);
    const int nriv = lbRival
                   + (((r0 & ~0x1FFu) >= thrF) ? 1 : 0) + (((r1 & ~0x1FFu) >= thrF) ? 1 : 0)
                   + (((r2 & ~0x1FFu) >= thrF) ? 1 : 0) + (((r3 & ~0x1FFu) >= thrF) ? 1 : 0);
    const int totr = nriv + __shfl_xor(nriv, 32);
    const int aovf = ovf | __shfl_xor(ovf, 32);

    // ---- exact resolution (only rows with rivals; verified chain) ----
    const float* zrow = &zl[PERM(rowl) * STR];
    const float  zn   = znl[rowl];

    int bkf;
    if (aovf) {
        // overflow fallback: full exact scan of this half's codes, asc k
        float bd = __builtin_inff(); int bq = 0x7FFFFFFF;
        for (int c = 0; c < 16; ++c)
#pragma unroll
            for (int qd = 0; qd < 4; ++qd)
#pragma unroll
                for (int i = 0; i < 4; ++i) {
                    const int k2 = c * 32 + qd * 8 + h * 4 + i;
                    const float dv = exact_dist(zrow, cb, enl, zn, k2);
                    if (dv < bd || (dv == bd && k2 < bq)) { bd = dv; bq = k2; }
                }
        const float obd = __shfl_xor(bd, 32);
        const int   obq = __shfl_xor(bq, 32);
        bkf = (obd < bd || (obd == bd && obq < bq)) ? obq : bq;
    } else if (totr > 0) {
        float bd = __builtin_inff(); bkf = 0x7FFFFFFF;
        if (((bk >> 2) & 1) == h) {       // owner half exact-dots screen best
            bd = exact_dist(zrow, cb, enl, zn, bk);
            bkf = bk;
        }
        if (lbRival) {                    // losing half's own best (R11 fix)
            const float dv = exact_dist(zrow, cb, enl, zn, bkL);
            if (dv < bd || (dv == bd && bkL < bkf)) { bd = dv; bkf = bkL; }
        }
#define TRYC(ri) if (((ri) & ~0x1FFu) >= thrF) { \
            const int k2 = (int)((ri) & 0x1FFu); \
            const float dv = exact_dist(zrow, cb, enl, zn, k2); \
            if (dv < bd || (dv == bd && k2 < bkf)) { bd = dv; bkf = k2; } }
        TRYC(r0) TRYC(r1) TRYC(r2) TRYC(r3)
#undef TRYC
        const float obd = __shfl_xor(bd, 32);
        const int   obq = __shfl_xor(bkf, 32);
        if (obd < bd || (obd == bd && obq < bkf)) bkf = obq;
    } else {
        bkf = bk;                         // no rival: screen best is proven
    }
    if (h == 0) {
        sfin[rowl] = bkf;
        idxout[(size_t)b * NT + tbase + rowl] = (float)bkf;
    }
    __syncthreads();

    // ---- staged epilogue (R8 verbatim) ----
    float* ech = zl;
#pragma unroll
    for (int j = 0; j < 8; ++j) {
        const int qq  = j * 256 + tid;
        const int row = qq >> 4, d4 = qq & 15;
        const float4 v = *(const float4*)(cb + (size_t)sfin[row] * ND + d4 * 4);
        float* dst = &ech[row * ESTR + d4 * 4];
        *(float2*)(dst)     = make_float2(v.x, v.y);
        *(float2*)(dst + 2) = make_float2(v.z, v.w);
    }
    __syncthreads();

    double lsum = 0.0;
#pragma unroll 4
    for (int j = 0; j < 32; ++j) {
        const int qq = j * 256 + tid;
        const int ir = qq & 127, d = qq >> 7;
        const float zv = z[zoff + (size_t)d * NT + ir];
        const float ev = ech[ir * ESTR + d];
        const float diff = __fsub_rn(ev, zv);              // quantized - zt
        qout[(size_t)b * (ND*NT) + (size_t)d * NT + tbase + ir] = __fadd_rn(zv, diff);
        lsum += (double)diff * (double)diff;
    }
#pragma unroll
    for (int off = 32; off > 0; off >>= 1) lsum += __shfl_down(lsum, off, 64);
    if ((tid & 63) == 0) sred[tid >> 6] = lsum;
    __syncthreads();

    if (tid == 0) {
        const double bsum = (sred[0] + sred[1]) + (sred[2] + sred[3]);
        atomicAdd(loss_acc, bsum);
        __threadfence();
        const uint32 old = atomicAdd(counter, 1u);
        if (old == (uint32)(NGRID - 1)) {
            __threadfence();
            const double tot = *(volatile double*)loss_acc;
            const double m = tot / (double)((size_t)NB * NT * ND);
            out0[0] = (float)(1.25 * m);   // codebook + 0.25*commitment
        }
    }
}

extern "C" void kernel_launch(void* const* d_in, const int* in_sizes, int n_in,
                              void* d_out, int out_size, void* d_ws, size_t ws_size,
                              hipStream_t stream) {
    const float* z  = (const float*)d_in[0];
    const float* cb = (const float*)d_in[1];

    float* out      = (float*)d_out;
    float* loss_out = out;                                  // 1 elem
    float* qout     = out + 1;                              // B*D*T
    float* idxout   = out + 1 + (size_t)NB * ND * NT;       // B*T

    // cbfrag 131072 B + 8192 B slack (c=15 prefetch overrun target, unused data)
    uint4*  cbfrag   = (uint4*)d_ws;
    float*  enorm    = (float*)((char*)d_ws + 139264);      // 2048 B
    double* loss_acc = (double*)((char*)d_ws + 141312);     // 8 B
    uint32* counter  = (uint32*)((char*)d_ws + 141320);     // 4 B

    prep_kernel<<<17, 256, 0, stream>>>(cb, cbfrag, enorm, loss_acc, counter);
    vq_main<<<NGRID, 256, 0, stream>>>(z, cb, cbfrag, enorm, qout, idxout,
                                       loss_acc, counter, loss_out);
}